// Round 2
// baseline (1377.514 us; speedup 1.0000x reference)
//
#include <hip/hip_runtime.h>
#include <hip/hip_bf16.h>
#include <cstdint>
#include <cstddef>

#define DI __device__ __forceinline__

// ---------- constants ----------
#define NB 4
#define NN 500
#define NQ 2000           // B*N
#define CD 256
#define NG 4
#define PIN 32
#define POUT 128
#define EFF 64
#define GTOT 32768        // G*TOTAL
#define LN_EPS 1e-5f

DI unsigned short f2bf(float f){
  unsigned u = __float_as_uint(f);
  return (unsigned short)((u + 0x7fffu + ((u>>16)&1u)) >> 16);
}
DI float bf2f(unsigned short s){ return __uint_as_float(((unsigned)s)<<16); }

DI void unpack8(uint4 r, float* f){
  f[0]=__uint_as_float(r.x<<16); f[1]=__uint_as_float(r.x & 0xffff0000u);
  f[2]=__uint_as_float(r.y<<16); f[3]=__uint_as_float(r.y & 0xffff0000u);
  f[4]=__uint_as_float(r.z<<16); f[5]=__uint_as_float(r.z & 0xffff0000u);
  f[6]=__uint_as_float(r.w<<16); f[7]=__uint_as_float(r.w & 0xffff0000u);
}

// block-wide (256 thr = 4 waves) sum of s, s2
DI void bred256(float& s, float& s2, float* red, int tid){
  #pragma unroll
  for(int off=32; off; off>>=1){
    s  += __shfl_xor(s,  off, 64);
    s2 += __shfl_xor(s2, off, 64);
  }
  int w = tid>>6;
  if((tid&63)==0){ red[w*2]=s; red[w*2+1]=s2; }
  __syncthreads();
  s  = red[0]+red[2]+red[4]+red[6];
  s2 = red[1]+red[3]+red[5]+red[7];
  __syncthreads();
}

// ---------- K0: feature transpose (B,C,H,W) f32 -> (B*G,H,W,64) bf16 ----------
__global__ __launch_bounds__(256) void k_transpose(const float* __restrict__ src,
    unsigned short* __restrict__ dst, int H, int W){
  __shared__ float tile[64][161];
  int bg = blockIdx.x / H, h = blockIdx.x % H;
  int b = bg >> 2, g = bg & 3;
  const float* s = src + (((size_t)(b*256 + g*64))*H + h)*(size_t)W;
  for(int idx=threadIdx.x; idx<64*W; idx+=256){
    int c = idx / W, w = idx - c*W;
    tile[c][w] = s[(size_t)c*H*W + w];
  }
  __syncthreads();
  unsigned short* d = dst + ((size_t)bg*H + h)*(size_t)W*64;
  for(int idx=threadIdx.x; idx<64*W; idx+=256){
    int w = idx>>6, c = idx&63;
    d[idx] = f2bf(tile[c][w]);
  }
}

// ---------- K1: offset GEMM + sample coords + level softmax ----------
__global__ __launch_bounds__(384) void k_off(const float* __restrict__ qf,
    const float* __restrict__ xyzr, const float* __restrict__ w_off,
    const float* __restrict__ b_off, float2* __restrict__ xyb, float4* __restrict__ lwb){
  __shared__ float qs[8][256];
  __shared__ float os[8][384];
  int q0 = blockIdx.x*8, tid = threadIdx.x;
  for(int idx=tid; idx<2048; idx+=384){
    int qq = idx>>8, k = idx&255;
    qs[qq][k] = qf[(size_t)(q0+qq)*256 + k];
  }
  __syncthreads();
  {
    int j = tid;
    float acc[8];
    #pragma unroll
    for(int i=0;i<8;i++) acc[i]=0.f;
    for(int k=0;k<256;k++){
      float w = w_off[(size_t)k*384 + j];
      #pragma unroll
      for(int qq=0;qq<8;qq++) acc[qq] += qs[qq][k]*w;
    }
    float bb = b_off[j];
    #pragma unroll
    for(int qq=0;qq<8;qq++) os[qq][j] = acc[qq] + bb;
  }
  __syncthreads();
  for(int idx=tid; idx<1024; idx+=384){
    int qq = idx>>7, gp = idx&127;
    int q = q0+qq;
    float4 xr = *(const float4*)&xyzr[(size_t)q*4];
    float rw = exp2f(xr.z - 0.5f*xr.w);
    float rh = exp2f(xr.z + 0.5f*xr.w);
    float sx = xr.x + os[qq][gp*3+0]*rw;
    float sy = xr.y + os[qq][gp*3+1]*rh;
    float lvl = xr.z + os[qq][gp*3+2] - 3.0f;
    float d0=lvl, d1=lvl-1.f, d2=lvl-2.f, d3=lvl-3.f;
    float e0=-0.5f*d0*d0, e1=-0.5f*d1*d1, e2=-0.5f*d2*d2, e3=-0.5f*d3*d3;
    float m = fmaxf(fmaxf(e0,e1),fmaxf(e2,e3));
    float x0=expf(e0-m), x1=expf(e1-m), x2=expf(e2-m), x3=expf(e3-m);
    float inv = 1.f/(x0+x1+x2+x3);
    xyb[(size_t)q*128+gp] = make_float2(sx,sy);
    lwb[(size_t)q*128+gp] = make_float4(x0*inv, x1*inv, x2*inv, x3*inv);
  }
}

// ---------- K2: params GEMM (rows [qbase,qlim) x256 @ 256x32768 + bias) -> bf16 chunk ----------
__global__ __launch_bounds__(256) void k_pgemm(const float* __restrict__ qf,
    const float* __restrict__ w_pg, const float* __restrict__ b_pg,
    unsigned short* __restrict__ par, int qbase, int qlim){
  __shared__ float qs[32][256];
  int qt = blockIdx.x >> 7, ct = blockIdx.x & 127;
  int q0 = qbase + qt*32;
  size_t c0 = (size_t)ct*256;
  int tid = threadIdx.x;
  for(int idx=tid; idx<8192; idx+=256){
    int qq = idx>>8, k = idx&255;
    int q = q0+qq;
    qs[qq][k] = (q<qlim) ? qf[(size_t)q*256 + k] : 0.f;
  }
  __syncthreads();
  int cg = tid & 63, qg = tid >> 6;
  size_t j0 = c0 + (size_t)cg*4;
  float acc[8][4];
  #pragma unroll
  for(int i=0;i<8;i++){ acc[i][0]=0;acc[i][1]=0;acc[i][2]=0;acc[i][3]=0; }
  const float* wp = w_pg + j0;
  for(int k=0;k<256;k++){
    float4 w = *(const float4*)&wp[(size_t)k*GTOT];
    #pragma unroll
    for(int qq=0;qq<8;qq++){
      float a = qs[qg*8+qq][k];
      acc[qq][0]+=a*w.x; acc[qq][1]+=a*w.y; acc[qq][2]+=a*w.z; acc[qq][3]+=a*w.w;
    }
  }
  float4 bb = *(const float4*)&b_pg[j0];
  #pragma unroll
  for(int qq=0;qq<8;qq++){
    int q = q0 + qg*8 + qq;
    if(q >= qlim) continue;
    ushort4 st;
    st.x = f2bf(acc[qq][0]+bb.x);
    st.y = f2bf(acc[qq][1]+bb.y);
    st.z = f2bf(acc[qq][2]+bb.z);
    st.w = f2bf(acc[qq][3]+bb.w);
    *(ushort4*)&par[(size_t)(q-qbase)*GTOT + j0] = st;
  }
}

// ---------- sampling helper ----------
DI float samp(const unsigned short* bp, int W, int H, int xi, int yi, float w){
  bool v = ((unsigned)xi < (unsigned)W) && ((unsigned)yi < (unsigned)H);
  int xc = min(max(xi,0),W-1), yc = min(max(yi,0),H-1);
  float val = bf2f(bp[((size_t)yc*W + xc)*64]);
  return v ? w*val : 0.f;
}

// ---------- K3: sampling + M/S mixing + two group-LN+relu -> out2 bf16 chunk ----------
__global__ __launch_bounds__(256) void k_mix(const unsigned short* __restrict__ featT,
    const float2* __restrict__ xyb, const float4* __restrict__ lwb,
    const unsigned short* __restrict__ par, unsigned short* __restrict__ out2,
    int qbase){
  __shared__ float xT[64][36];    // [c][p]
  __shared__ float Ms[64][64];    // [c][d]
  __shared__ float o1[32][64];    // [p][d]
  __shared__ float ST[32][132];   // [p][o]
  __shared__ float red[8];
  int lq = blockIdx.x >> 2, g = blockIdx.x & 3;
  int q = qbase + lq;
  int b = q / NN;
  int bg = b*4 + g;
  int tid = threadIdx.x;
  int c = tid & 63, pg = tid >> 6;

  const int HH[4] = {100,50,25,13};
  const int WW[4] = {160,80,40,20};
  const float IS[4] = {0.125f, 0.0625f, 0.03125f, 0.015625f};
  const size_t LO[4] = {0ull, 16384000ull, 20480000ull, 21504000ull};

  // Phase A: bilinear gather into xT[c][p]
  for(int i=0;i<8;i++){
    int p = i*4 + pg;
    int pi = q*128 + g*32 + p;
    float2 xy = xyb[pi];
    float4 lw = lwb[pi];
    float acc = 0.f;
    #pragma unroll
    for(int l=0;l<4;l++){
      int H = HH[l], W = WW[l];
      float px = xy.x*IS[l] - 0.5f;
      float py = xy.y*IS[l] - 0.5f;
      float xf = floorf(px), yf = floorf(py);
      float wx = px - xf, wy = py - yf;
      int x0 = (int)xf, y0 = (int)yf;
      const unsigned short* bp = featT + LO[l] + (size_t)bg*H*W*64 + c;
      float s = 0.f;
      s += samp(bp,W,H,x0  ,y0  ,(1.f-wx)*(1.f-wy));
      s += samp(bp,W,H,x0+1,y0  ,wx*(1.f-wy));
      s += samp(bp,W,H,x0  ,y0+1,(1.f-wx)*wy);
      s += samp(bp,W,H,x0+1,y0+1,wx*wy);
      float lwl = (l==0)?lw.x:((l==1)?lw.y:((l==2)?lw.z:lw.w));
      acc += lwl*s;
    }
    xT[c][p] = acc;
  }

  // load M (first 4096 bf16 of this g) and S (next 4096)
  const unsigned short* pb = par + (size_t)lq*GTOT + (size_t)g*8192;
  float* msf = &Ms[0][0];
  #pragma unroll
  for(int it=0; it<2; it++){
    int off = it*2048 + tid*8;
    uint4 rawm = *(const uint4*)(pb + off);
    float fm[8]; unpack8(rawm, fm);
    #pragma unroll
    for(int j=0;j<8;j++) msf[off+j] = fm[j];
    uint4 raws = *(const uint4*)(pb + 4096 + off);
    float fs[8]; unpack8(raws, fs);
    int o = off >> 5, p0 = off & 31;
    #pragma unroll
    for(int j=0;j<8;j++) ST[p0+j][o] = fs[j];
  }
  __syncthreads();

  // Phase B: out1 = x @ M, group-LN over 32x64, relu
  int d = tid & 63;
  float fb[8];
  #pragma unroll
  for(int i=0;i<8;i++) fb[i]=0.f;
  for(int cc=0; cc<64; cc++){
    float m = Ms[cc][d];
    float4 a0 = *(const float4*)&xT[cc][pg*8];
    float4 a1 = *(const float4*)&xT[cc][pg*8+4];
    fb[0]+=a0.x*m; fb[1]+=a0.y*m; fb[2]+=a0.z*m; fb[3]+=a0.w*m;
    fb[4]+=a1.x*m; fb[5]+=a1.y*m; fb[6]+=a1.z*m; fb[7]+=a1.w*m;
  }
  float s=0.f, s2=0.f;
  #pragma unroll
  for(int i=0;i<8;i++){ s+=fb[i]; s2+=fb[i]*fb[i]; }
  bred256(s,s2,red,tid);
  {
    float mean = s*(1.f/2048.f);
    float var = s2*(1.f/2048.f) - mean*mean;
    float rs = rsqrtf(var + LN_EPS);
    #pragma unroll
    for(int i=0;i<8;i++){
      float v = (fb[i]-mean)*rs;
      o1[pg*8+i][d] = v>0.f ? v : 0.f;
    }
  }
  __syncthreads();

  // Phase C: out2 = S @ out1, group-LN over 128x64, relu -> bf16 store
  float fc[32];
  #pragma unroll
  for(int i=0;i<32;i++) fc[i]=0.f;
  for(int p=0;p<32;p++){
    float v = o1[p][d];
    #pragma unroll
    for(int jj=0;jj<8;jj++){
      float4 sv = *(const float4*)&ST[p][pg*32 + jj*4];
      fc[jj*4+0]+=sv.x*v; fc[jj*4+1]+=sv.y*v; fc[jj*4+2]+=sv.z*v; fc[jj*4+3]+=sv.w*v;
    }
  }
  s=0.f; s2=0.f;
  #pragma unroll
  for(int i=0;i<32;i++){ s+=fc[i]; s2+=fc[i]*fc[i]; }
  bred256(s,s2,red,tid);
  {
    float mean = s*(1.f/8192.f);
    float var = s2*(1.f/8192.f) - mean*mean;
    float rs = rsqrtf(var + LN_EPS);
    unsigned short* ob = out2 + (size_t)lq*GTOT + (size_t)g*8192 + d;
    #pragma unroll
    for(int i=0;i<32;i++){
      float v = (fc[i]-mean)*rs;
      v = v>0.f ? v : 0.f;
      ob[(size_t)(pg*32+i)*64] = f2bf(v);
    }
  }
}

// ---------- K4: final GEMM (chunk rows x32768 bf16 @ 32768x256 f32), K-split x16 ----------
DI uint4 zero4(){ uint4 z; z.x=0;z.y=0;z.z=0;z.w=0; return z; }

__global__ __launch_bounds__(256) void k_fgemm(const unsigned short* __restrict__ A,
    const float* __restrict__ w_out, float* __restrict__ part, int qbase, int qlim){
  __shared__ float As[64][36];   // [kk][q]
  int ks = blockIdx.x & 15, qt = blockIdx.x >> 4;
  int q0 = qbase + qt*32, kbase = ks*2048;
  int tid = threadIdx.x;
  int qq = tid>>3, k8 = (tid&7)*8;
  int jh = tid & 127, qh = tid>>7;
  float acc[16][2];
  #pragma unroll
  for(int i=0;i<16;i++){ acc[i][0]=0.f; acc[i][1]=0.f; }

  int q = q0 + qq;
  const unsigned short* abase = A + (size_t)(q-qbase)*GTOT + k8;
  uint4 raw = (q<qlim) ? *(const uint4*)(abase + kbase) : zero4();

  for(int kc=kbase; kc<kbase+2048; kc+=64){
    float f[8]; unpack8(raw, f);
    __syncthreads();
    #pragma unroll
    for(int i=0;i<8;i++) As[k8+i][qq] = f[i];
    __syncthreads();
    if(kc+64 < kbase+2048) raw = (q<qlim) ? *(const uint4*)(abase + kc + 64) : zero4();
    const float* wrow = w_out + (size_t)kc*256 + jh*2;
    #pragma unroll 4
    for(int kk=0;kk<64;kk++){
      float2 wv = *(const float2*)(wrow + (size_t)kk*256);
      const float* ar = &As[kk][qh*16];
      #pragma unroll
      for(int i=0;i<4;i++){
        float4 a = *(const float4*)(ar + i*4);
        acc[i*4+0][0]+=a.x*wv.x; acc[i*4+0][1]+=a.x*wv.y;
        acc[i*4+1][0]+=a.y*wv.x; acc[i*4+1][1]+=a.y*wv.y;
        acc[i*4+2][0]+=a.z*wv.x; acc[i*4+2][1]+=a.z*wv.y;
        acc[i*4+3][0]+=a.w*wv.x; acc[i*4+3][1]+=a.w*wv.y;
      }
    }
  }
  float* pp = part + (size_t)ks*NQ*256;
  #pragma unroll
  for(int i=0;i<16;i++){
    int qs_ = q0 + qh*16 + i;
    if(qs_ < qlim){
      *(float2*)&pp[(size_t)qs_*256 + jh*2] = make_float2(acc[i][0], acc[i][1]);
    }
  }
}

// ---------- K5: K-split reduce + bias + residual + LayerNorm ----------
__global__ __launch_bounds__(256) void k_ln(const float* __restrict__ part,
    const float* __restrict__ qf, const float* __restrict__ b_out,
    const float* __restrict__ ln_g, const float* __restrict__ ln_b,
    float* __restrict__ out){
  __shared__ float red[8];
  int q = blockIdx.x, j = threadIdx.x;
  float s = qf[(size_t)q*256 + j] + b_out[j];
  #pragma unroll
  for(int ks=0; ks<16; ks++) s += part[((size_t)ks*NQ + q)*256 + j];
  float a = s, a2 = s*s;
  bred256(a, a2, red, j);
  float mean = a*(1.f/256.f);
  float var = a2*(1.f/256.f) - mean*mean;
  float rs = rsqrtf(var + LN_EPS);
  out[(size_t)q*256 + j] = (s-mean)*rs*ln_g[j] + ln_b[j];
}

// ---------- launch ----------
extern "C" void kernel_launch(void* const* d_in, const int* in_sizes, int n_in,
                              void* d_out, int out_size, void* d_ws, size_t ws_size,
                              hipStream_t stream) {
  const float* feat0 = (const float*)d_in[0];
  const float* feat1 = (const float*)d_in[1];
  const float* feat2 = (const float*)d_in[2];
  const float* feat3 = (const float*)d_in[3];
  const float* qf    = (const float*)d_in[4];
  const float* xyzr  = (const float*)d_in[5];
  const float* w_off = (const float*)d_in[6];
  const float* b_off = (const float*)d_in[7];
  const float* w_pg  = (const float*)d_in[8];
  const float* b_pg  = (const float*)d_in[9];
  const float* w_out = (const float*)d_in[10];
  const float* b_out = (const float*)d_in[11];
  const float* ln_g  = (const float*)d_in[12];
  const float* ln_b  = (const float*)d_in[13];

  // workspace layout (256B aligned), chunk count chosen from ws_size
  size_t off = 0;
  auto alloc = [&](size_t bytes){ size_t r = off; off = (off + bytes + 255) & ~255ull; return r; };
  size_t oFEAT = alloc(43540480ull);            // featT bf16
  size_t oXY   = alloc((size_t)NQ*128*8);       // float2
  size_t oLW   = alloc((size_t)NQ*128*16);      // float4
  size_t oPART = alloc((size_t)16*NQ*256*4);    // f32 partials
  size_t fixedEnd = off;

  int NC = 0;
  size_t cb = 0;
  for (int t = 1; t <= 8; t *= 2) {
    size_t c = (((size_t)(NQ/t)*GTOT*2) + 255) & ~255ull;
    if (fixedEnd + 2*c <= ws_size) { NC = t; cb = c; break; }
  }
  if (NC == 0) return;  // workspace too small: leave output poisoned (validation fail, not crash)
  size_t oPAR = fixedEnd, oOUT2 = fixedEnd + cb;

  char* ws = (char*)d_ws;
  unsigned short* featT = (unsigned short*)(ws + oFEAT);
  float2* xyb = (float2*)(ws + oXY);
  float4* lwb = (float4*)(ws + oLW);
  float* part = (float*)(ws + oPART);
  unsigned short* par  = (unsigned short*)(ws + oPAR);
  unsigned short* o2   = (unsigned short*)(ws + oOUT2);

  k_transpose<<<16*100, 256, 0, stream>>>(feat0, featT + 0ull,        100, 160);
  k_transpose<<<16*50,  256, 0, stream>>>(feat1, featT + 16384000ull,  50,  80);
  k_transpose<<<16*25,  256, 0, stream>>>(feat2, featT + 20480000ull,  25,  40);
  k_transpose<<<16*13,  256, 0, stream>>>(feat3, featT + 21504000ull,  13,  20);
  k_off<<<250, 384, 0, stream>>>(qf, xyzr, w_off, b_off, xyb, lwb);

  int qcount = NQ / NC;
  for (int c = 0; c < NC; ++c) {
    int qbase = c * qcount;
    int qlim  = qbase + qcount;
    int ntiles = (qcount + 31) / 32;
    k_pgemm<<<ntiles*128, 256, 0, stream>>>(qf, w_pg, b_pg, par, qbase, qlim);
    k_mix<<<qcount*4, 256, 0, stream>>>(featT, xyb, lwb, par, o2, qbase);
    k_fgemm<<<ntiles*16, 256, 0, stream>>>(o2, w_out, part, qbase, qlim);
  }
  k_ln<<<NQ, 256, 0, stream>>>(part, qf, b_out, ln_g, ln_b, (float*)d_out);
}

// Round 3
// 510.179 us; speedup vs baseline: 2.7001x; 2.7001x over previous
//
#include <hip/hip_runtime.h>
#include <hip/hip_bf16.h>
#include <cstdint>
#include <cstddef>

#define DI __device__ __forceinline__

// ---------- constants ----------
#define NN 500
#define NQ 2000           // B*N
#define GTOT 32768        // G*TOTAL
#define LN_EPS 1e-5f

typedef __attribute__((ext_vector_type(8))) short short8v;
typedef __attribute__((ext_vector_type(4))) float f32x4;

DI unsigned short f2bf(float f){
  unsigned u = __float_as_uint(f);
  return (unsigned short)((u + 0x7fffu + ((u>>16)&1u)) >> 16);
}
DI float bf2f(unsigned short s){ return __uint_as_float(((unsigned)s)<<16); }

DI void unpack8(uint4 r, float* f){
  f[0]=__uint_as_float(r.x<<16); f[1]=__uint_as_float(r.x & 0xffff0000u);
  f[2]=__uint_as_float(r.y<<16); f[3]=__uint_as_float(r.y & 0xffff0000u);
  f[4]=__uint_as_float(r.z<<16); f[5]=__uint_as_float(r.z & 0xffff0000u);
  f[6]=__uint_as_float(r.w<<16); f[7]=__uint_as_float(r.w & 0xffff0000u);
}

// block-wide (256 thr = 4 waves) sum of s, s2
DI void bred256(float& s, float& s2, float* red, int tid){
  #pragma unroll
  for(int off=32; off; off>>=1){
    s  += __shfl_xor(s,  off, 64);
    s2 += __shfl_xor(s2, off, 64);
  }
  int w = tid>>6;
  if((tid&63)==0){ red[w*2]=s; red[w*2+1]=s2; }
  __syncthreads();
  s  = red[0]+red[2]+red[4]+red[6];
  s2 = red[1]+red[3]+red[5]+red[7];
  __syncthreads();
}

// ---------- K0: feature transpose (B,C,H,W) f32 -> (B*G,H,W,64) bf16 ----------
__global__ __launch_bounds__(256) void k_transpose(const float* __restrict__ src,
    unsigned short* __restrict__ dst, int H, int W){
  __shared__ float tile[64][161];
  int bg = blockIdx.x / H, h = blockIdx.x % H;
  int b = bg >> 2, g = bg & 3;
  const float* s = src + (((size_t)(b*256 + g*64))*H + h)*(size_t)W;
  for(int idx=threadIdx.x; idx<64*W; idx+=256){
    int c = idx / W, w = idx - c*W;
    tile[c][w] = s[(size_t)c*H*W + w];
  }
  __syncthreads();
  unsigned short* d = dst + ((size_t)bg*H + h)*(size_t)W*64;
  for(int idx=threadIdx.x; idx<64*W; idx+=256){
    int w = idx>>6, c = idx&63;
    d[idx] = f2bf(tile[c][w]);
  }
}

// ---------- K1: offset GEMM + sample coords + level softmax ----------
__global__ __launch_bounds__(384) void k_off(const float* __restrict__ qf,
    const float* __restrict__ xyzr, const float* __restrict__ w_off,
    const float* __restrict__ b_off, float2* __restrict__ xyb, float4* __restrict__ lwb){
  __shared__ float qs[8][256];
  __shared__ float os[8][384];
  int q0 = blockIdx.x*8, tid = threadIdx.x;
  for(int idx=tid; idx<2048; idx+=384){
    int qq = idx>>8, k = idx&255;
    qs[qq][k] = qf[(size_t)(q0+qq)*256 + k];
  }
  __syncthreads();
  {
    int j = tid;
    float acc[8];
    #pragma unroll
    for(int i=0;i<8;i++) acc[i]=0.f;
    for(int k=0;k<256;k++){
      float w = w_off[(size_t)k*384 + j];
      #pragma unroll
      for(int qq=0;qq<8;qq++) acc[qq] += qs[qq][k]*w;
    }
    float bb = b_off[j];
    #pragma unroll
    for(int qq=0;qq<8;qq++) os[qq][j] = acc[qq] + bb;
  }
  __syncthreads();
  for(int idx=tid; idx<1024; idx+=384){
    int qq = idx>>7, gp = idx&127;
    int q = q0+qq;
    float4 xr = *(const float4*)&xyzr[(size_t)q*4];
    float rw = exp2f(xr.z - 0.5f*xr.w);
    float rh = exp2f(xr.z + 0.5f*xr.w);
    float sx = xr.x + os[qq][gp*3+0]*rw;
    float sy = xr.y + os[qq][gp*3+1]*rh;
    float lvl = xr.z + os[qq][gp*3+2] - 3.0f;
    float d0=lvl, d1=lvl-1.f, d2=lvl-2.f, d3=lvl-3.f;
    float e0=-0.5f*d0*d0, e1=-0.5f*d1*d1, e2=-0.5f*d2*d2, e3=-0.5f*d3*d3;
    float m = fmaxf(fmaxf(e0,e1),fmaxf(e2,e3));
    float x0=expf(e0-m), x1=expf(e1-m), x2=expf(e2-m), x3=expf(e3-m);
    float inv = 1.f/(x0+x1+x2+x3);
    xyb[(size_t)q*128+gp] = make_float2(sx,sy);
    lwb[(size_t)q*128+gp] = make_float4(x0*inv, x1*inv, x2*inv, x3*inv);
  }
}

// ---------- K-cvt: qf f32[2000][256] -> bf16[2048][256], pad rows zeroed ----------
__global__ __launch_bounds__(256) void k_cvtqf(const float* __restrict__ qf,
    unsigned short* __restrict__ qfb){
  int idx = blockIdx.x*256 + threadIdx.x;   // one per 8 elems; 65536 total
  size_t base = (size_t)idx*8;
  int row = idx >> 5;
  ushort4 lo, hi;
  if(row < NQ){
    float4 a = *(const float4*)(qf + base);
    float4 b = *(const float4*)(qf + base + 4);
    lo.x=f2bf(a.x); lo.y=f2bf(a.y); lo.z=f2bf(a.z); lo.w=f2bf(a.w);
    hi.x=f2bf(b.x); hi.y=f2bf(b.y); hi.z=f2bf(b.z); hi.w=f2bf(b.w);
  } else {
    lo.x=lo.y=lo.z=lo.w=0; hi.x=hi.y=hi.z=hi.w=0;
  }
  *(ushort4*)(qfb + base) = lo;
  *(ushort4*)(qfb + base + 4) = hi;
}

// ---------- K-trcvt: src f32 [R][C] -> dst bf16 [C][R] (R,C multiples of 64) ----------
__global__ __launch_bounds__(256) void k_trcvt(const float* __restrict__ src,
    unsigned short* __restrict__ dst, int R, int C){
  __shared__ float tile[64][65];
  int ctiles = C >> 6;
  int rt = blockIdx.x / ctiles, ct = blockIdx.x % ctiles;
  int r0 = rt<<6, c0 = ct<<6;
  int tid = threadIdx.x;
  int lr = tid>>6, lc = tid&63;
  #pragma unroll
  for(int i=0;i<16;i++)
    tile[lr + i*4][lc] = src[(size_t)(r0+lr+i*4)*C + c0+lc];
  __syncthreads();
  #pragma unroll
  for(int i=0;i<16;i++)
    dst[(size_t)(c0+lr+i*4)*R + r0+lc] = f2bf(tile[lc][lr+i*4]);
}

// ---------- shared MFMA tile compute: 64x64 tile, BK=128, swizzled LDS ----------
DI f32x4 mfma16(short8v a, short8v b, f32x4 c){
  return __builtin_amdgcn_mfma_f32_16x16x32_bf16(a, b, c, 0, 0, 0);
}

DI void mma_step(const short* lsA, const short* lsB, int wm, int wn, int lane,
                 f32x4 acc[2][2]){
  #pragma unroll
  for(int ks=0; ks<4; ks++){
    short8v a[2], b[2];
    #pragma unroll
    for(int i=0;i<2;i++){
      int ra = wm*32 + i*16 + (lane&15);
      int ba = (ra<<8) + ks*64 + ((lane>>4)<<4);
      ba ^= (ra&7)<<4;
      a[i] = *(const short8v*)((const char*)lsA + ba);
      int rb = wn*32 + i*16 + (lane&15);
      int bb = (rb<<8) + ks*64 + ((lane>>4)<<4);
      bb ^= (rb&7)<<4;
      b[i] = *(const short8v*)((const char*)lsB + bb);
    }
    #pragma unroll
    for(int mi=0;mi<2;mi++)
      #pragma unroll
      for(int ni=0;ni<2;ni++)
        acc[mi][ni] = mfma16(a[mi], b[ni], acc[mi][ni]);
  }
}

// stage a 64x128 bf16 tile (global row-major, row stride ldk shorts) into swizzled LDS
DI void stage64x128(const unsigned short* __restrict__ g, size_t row0, size_t ldk,
                    int k0, short* lds, int tid){
  #pragma unroll
  for(int i=0;i<4;i++){
    int idx = tid + i*256;
    int r = idx>>4, c = idx&15;
    uint4 v = *(const uint4*)(g + (row0 + r)*ldk + k0 + c*8);
    int byte = (r<<8) + (c<<4);
    byte ^= (r&7)<<4;
    *(uint4*)((char*)lds + byte) = v;
  }
}

// ---------- K2: params GEMM via MFMA: par[q][32768] = qfb @ wpgT^T + b_pg ----------
__global__ __launch_bounds__(256) void k_pgemm_mfma(const unsigned short* __restrict__ qfb,
    const unsigned short* __restrict__ wpgT, const float* __restrict__ b_pg,
    unsigned short* __restrict__ par, int qbase, int qlim, int mtiles){
  __shared__ short lsA[64*128], lsB[64*128];
  int mt = blockIdx.x % mtiles, nt = blockIdx.x / mtiles;
  int m0 = mt*64;
  size_t n0 = (size_t)nt*64;
  int tid = threadIdx.x, lane = tid&63, wv = tid>>6;
  int wm = wv>>1, wn = wv&1;
  f32x4 acc[2][2] = {};
  #pragma unroll
  for(int kb=0; kb<2; kb++){
    int k0 = kb*128;
    stage64x128(qfb, (size_t)(qbase+m0), 256, k0, lsA, tid);
    stage64x128(wpgT, n0, 256, k0, lsB, tid);
    __syncthreads();
    mma_step(lsA, lsB, wm, wn, lane, acc);
    __syncthreads();
  }
  int colb = (int)n0 + wn*32 + (lane&15);
  int rowb = m0 + wm*32 + ((lane>>4)<<2);
  #pragma unroll
  for(int ni=0;ni<2;ni++){
    int col = colb + ni*16;
    float bias = b_pg[col];
    #pragma unroll
    for(int mi=0;mi<2;mi++){
      #pragma unroll
      for(int j=0;j<4;j++){
        int r = rowb + mi*16 + j;
        if(qbase + r < qlim)
          par[(size_t)r*GTOT + col] = f2bf(acc[mi][ni][j] + bias);
      }
    }
  }
}

// ---------- K4: final GEMM via MFMA, K-split x16 -> f32 partials ----------
__global__ __launch_bounds__(256) void k_fgemm_mfma(const unsigned short* __restrict__ A,
    const unsigned short* __restrict__ woutT, float* __restrict__ part,
    int qbase, int qlim, int mtiles){
  __shared__ short lsA[64*128], lsB[64*128];
  int bid = blockIdx.x;
  int mt = bid % mtiles; bid /= mtiles;
  int nt = bid & 3, ks = bid >> 2;
  int m0 = mt*64, n0 = nt*64;
  int tid = threadIdx.x, lane = tid&63, wv = tid>>6;
  int wm = wv>>1, wn = wv&1;
  f32x4 acc[2][2] = {};
  int kbase = ks*2048;
  for(int k0=kbase; k0<kbase+2048; k0+=128){
    stage64x128(A, (size_t)m0, GTOT, k0, lsA, tid);
    stage64x128(woutT, (size_t)n0, GTOT, k0, lsB, tid);
    __syncthreads();
    mma_step(lsA, lsB, wm, wn, lane, acc);
    __syncthreads();
  }
  float* pp = part + (size_t)ks*NQ*256;
  int colb = n0 + wn*32 + (lane&15);
  int rowb = m0 + wm*32 + ((lane>>4)<<2);
  #pragma unroll
  for(int mi=0;mi<2;mi++)
    #pragma unroll
    for(int ni=0;ni<2;ni++)
      #pragma unroll
      for(int j=0;j<4;j++){
        int r = rowb + mi*16 + j;
        if(qbase + r < qlim)
          pp[(size_t)(qbase + r)*256 + colb + ni*16] = acc[mi][ni][j];
      }
}

// ---------- sampling helper ----------
DI float samp(const unsigned short* bp, int W, int H, int xi, int yi, float w){
  bool v = ((unsigned)xi < (unsigned)W) && ((unsigned)yi < (unsigned)H);
  int xc = min(max(xi,0),W-1), yc = min(max(yi,0),H-1);
  float val = bf2f(bp[((size_t)yc*W + xc)*64]);
  return v ? w*val : 0.f;
}

// ---------- K3: sampling + M/S mixing + two group-LN+relu -> out2 bf16 chunk ----------
__global__ __launch_bounds__(256) void k_mix(const unsigned short* __restrict__ featT,
    const float2* __restrict__ xyb, const float4* __restrict__ lwb,
    const unsigned short* __restrict__ par, unsigned short* __restrict__ out2,
    int qbase){
  __shared__ float xT[64][36];    // [c][p]
  __shared__ float Ms[64][64];    // [c][d]
  __shared__ float o1[32][64];    // [p][d]
  __shared__ float ST[32][132];   // [p][o]
  __shared__ float red[8];
  int lq = blockIdx.x >> 2, g = blockIdx.x & 3;
  int q = qbase + lq;
  int b = q / NN;
  int bg = b*4 + g;
  int tid = threadIdx.x;
  int c = tid & 63, pg = tid >> 6;

  const int HH[4] = {100,50,25,13};
  const int WW[4] = {160,80,40,20};
  const float IS[4] = {0.125f, 0.0625f, 0.03125f, 0.015625f};
  const size_t LO[4] = {0ull, 16384000ull, 20480000ull, 21504000ull};

  for(int i=0;i<8;i++){
    int p = i*4 + pg;
    int pi = q*128 + g*32 + p;
    float2 xy = xyb[pi];
    float4 lw = lwb[pi];
    float acc = 0.f;
    #pragma unroll
    for(int l=0;l<4;l++){
      int H = HH[l], W = WW[l];
      float px = xy.x*IS[l] - 0.5f;
      float py = xy.y*IS[l] - 0.5f;
      float xf = floorf(px), yf = floorf(py);
      float wx = px - xf, wy = py - yf;
      int x0 = (int)xf, y0 = (int)yf;
      const unsigned short* bp = featT + LO[l] + (size_t)bg*H*W*64 + c;
      float s = 0.f;
      s += samp(bp,W,H,x0  ,y0  ,(1.f-wx)*(1.f-wy));
      s += samp(bp,W,H,x0+1,y0  ,wx*(1.f-wy));
      s += samp(bp,W,H,x0  ,y0+1,(1.f-wx)*wy);
      s += samp(bp,W,H,x0+1,y0+1,wx*wy);
      float lwl = (l==0)?lw.x:((l==1)?lw.y:((l==2)?lw.z:lw.w));
      acc += lwl*s;
    }
    xT[c][p] = acc;
  }

  const unsigned short* pb = par + (size_t)lq*GTOT + (size_t)g*8192;
  float* msf = &Ms[0][0];
  #pragma unroll
  for(int it=0; it<2; it++){
    int off = it*2048 + tid*8;
    uint4 rawm = *(const uint4*)(pb + off);
    float fm[8]; unpack8(rawm, fm);
    #pragma unroll
    for(int j=0;j<8;j++) msf[off+j] = fm[j];
    uint4 raws = *(const uint4*)(pb + 4096 + off);
    float fs[8]; unpack8(raws, fs);
    int o = off >> 5, p0 = off & 31;
    #pragma unroll
    for(int j=0;j<8;j++) ST[p0+j][o] = fs[j];
  }
  __syncthreads();

  int d = tid & 63;
  float fb[8];
  #pragma unroll
  for(int i=0;i<8;i++) fb[i]=0.f;
  for(int cc=0; cc<64; cc++){
    float m = Ms[cc][d];
    float4 a0 = *(const float4*)&xT[cc][pg*8];
    float4 a1 = *(const float4*)&xT[cc][pg*8+4];
    fb[0]+=a0.x*m; fb[1]+=a0.y*m; fb[2]+=a0.z*m; fb[3]+=a0.w*m;
    fb[4]+=a1.x*m; fb[5]+=a1.y*m; fb[6]+=a1.z*m; fb[7]+=a1.w*m;
  }
  float s=0.f, s2=0.f;
  #pragma unroll
  for(int i=0;i<8;i++){ s+=fb[i]; s2+=fb[i]*fb[i]; }
  bred256(s,s2,red,tid);
  {
    float mean = s*(1.f/2048.f);
    float var = s2*(1.f/2048.f) - mean*mean;
    float rs = rsqrtf(var + LN_EPS);
    #pragma unroll
    for(int i=0;i<8;i++){
      float v = (fb[i]-mean)*rs;
      o1[pg*8+i][d] = v>0.f ? v : 0.f;
    }
  }
  __syncthreads();

  float fc[32];
  #pragma unroll
  for(int i=0;i<32;i++) fc[i]=0.f;
  for(int p=0;p<32;p++){
    float v = o1[p][d];
    #pragma unroll
    for(int jj=0;jj<8;jj++){
      float4 sv = *(const float4*)&ST[p][pg*32 + jj*4];
      fc[jj*4+0]+=sv.x*v; fc[jj*4+1]+=sv.y*v; fc[jj*4+2]+=sv.z*v; fc[jj*4+3]+=sv.w*v;
    }
  }
  s=0.f; s2=0.f;
  #pragma unroll
  for(int i=0;i<32;i++){ s+=fc[i]; s2+=fc[i]*fc[i]; }
  bred256(s,s2,red,tid);
  {
    float mean = s*(1.f/8192.f);
    float var = s2*(1.f/8192.f) - mean*mean;
    float rs = rsqrtf(var + LN_EPS);
    unsigned short* ob = out2 + (size_t)lq*GTOT + (size_t)g*8192 + d;
    #pragma unroll
    for(int i=0;i<32;i++){
      float v = (fc[i]-mean)*rs;
      v = v>0.f ? v : 0.f;
      ob[(size_t)(pg*32+i)*64] = f2bf(v);
    }
  }
}

// ---------- K5: K-split reduce + bias + residual + LayerNorm ----------
__global__ __launch_bounds__(256) void k_ln(const float* __restrict__ part,
    const float* __restrict__ qf, const float* __restrict__ b_out,
    const float* __restrict__ ln_g, const float* __restrict__ ln_b,
    float* __restrict__ out){
  __shared__ float red[8];
  int q = blockIdx.x, j = threadIdx.x;
  float s = qf[(size_t)q*256 + j] + b_out[j];
  #pragma unroll
  for(int ks=0; ks<16; ks++) s += part[((size_t)ks*NQ + q)*256 + j];
  float a = s, a2 = s*s;
  bred256(a, a2, red, j);
  float mean = a*(1.f/256.f);
  float var = a2*(1.f/256.f) - mean*mean;
  float rs = rsqrtf(var + LN_EPS);
  out[(size_t)q*256 + j] = (s-mean)*rs*ln_g[j] + ln_b[j];
}

// ---------- launch ----------
extern "C" void kernel_launch(void* const* d_in, const int* in_sizes, int n_in,
                              void* d_out, int out_size, void* d_ws, size_t ws_size,
                              hipStream_t stream) {
  const float* feat0 = (const float*)d_in[0];
  const float* feat1 = (const float*)d_in[1];
  const float* feat2 = (const float*)d_in[2];
  const float* feat3 = (const float*)d_in[3];
  const float* qf    = (const float*)d_in[4];
  const float* xyzr  = (const float*)d_in[5];
  const float* w_off = (const float*)d_in[6];
  const float* b_off = (const float*)d_in[7];
  const float* w_pg  = (const float*)d_in[8];
  const float* b_pg  = (const float*)d_in[9];
  const float* w_out = (const float*)d_in[10];
  const float* b_out = (const float*)d_in[11];
  const float* ln_g  = (const float*)d_in[12];
  const float* ln_b  = (const float*)d_in[13];

  size_t off = 0;
  auto alloc = [&](size_t bytes){ size_t r = off; off = (off + bytes + 255) & ~255ull; return r; };
  size_t oFEAT = alloc(43540480ull);              // featT bf16
  size_t oXY   = alloc((size_t)NQ*128*8);         // float2
  size_t oLW   = alloc((size_t)NQ*128*16);        // float4
  size_t oPART = alloc((size_t)16*NQ*256*4);      // f32 partials
  size_t oQFB  = alloc((size_t)2048*256*2);       // qf bf16 padded
  size_t oWPGT = alloc((size_t)GTOT*256*2);       // w_pg^T bf16
  size_t oWOUT = alloc((size_t)256*GTOT*2);       // w_out^T bf16
  size_t fixedEnd = off;

  int NC = 0; size_t cb = 0; int qcount = 0, qpad = 0;
  for (int t = 1; t <= 8; t *= 2) {
    int qc = NQ / t;
    int qp = (qc + 63) & ~63;
    size_t c = (((size_t)qp*GTOT*2) + 255) & ~255ull;
    if (fixedEnd + 2*c <= ws_size) { NC = t; cb = c; qcount = qc; qpad = qp; break; }
  }
  if (NC == 0) return;
  size_t oPAR = fixedEnd, oOUT2 = fixedEnd + cb;

  char* ws = (char*)d_ws;
  unsigned short* featT = (unsigned short*)(ws + oFEAT);
  float2* xyb = (float2*)(ws + oXY);
  float4* lwb = (float4*)(ws + oLW);
  float* part = (float*)(ws + oPART);
  unsigned short* qfb  = (unsigned short*)(ws + oQFB);
  unsigned short* wpgT = (unsigned short*)(ws + oWPGT);
  unsigned short* woutT= (unsigned short*)(ws + oWOUT);
  unsigned short* par  = (unsigned short*)(ws + oPAR);
  unsigned short* o2   = (unsigned short*)(ws + oOUT2);

  k_transpose<<<16*100, 256, 0, stream>>>(feat0, featT + 0ull,        100, 160);
  k_transpose<<<16*50,  256, 0, stream>>>(feat1, featT + 16384000ull,  50,  80);
  k_transpose<<<16*25,  256, 0, stream>>>(feat2, featT + 20480000ull,  25,  40);
  k_transpose<<<16*13,  256, 0, stream>>>(feat3, featT + 21504000ull,  13,  20);
  k_off<<<250, 384, 0, stream>>>(qf, xyzr, w_off, b_off, xyb, lwb);
  k_cvtqf<<<256, 256, 0, stream>>>(qf, qfb);
  k_trcvt<<<2048, 256, 0, stream>>>(w_pg,  wpgT, 256, GTOT);   // [256][32768] -> [32768][256]
  k_trcvt<<<2048, 256, 0, stream>>>(w_out, woutT, GTOT, 256);  // [32768][256] -> [256][32768]

  int mtiles = qpad / 64;
  for (int c = 0; c < NC; ++c) {
    int qbase = c * qcount;
    int qlim  = qbase + qcount;
    k_pgemm_mfma<<<mtiles*512, 256, 0, stream>>>(qfb, wpgT, b_pg, par, qbase, qlim, mtiles);
    k_mix<<<qcount*4, 256, 0, stream>>>(featT, xyb, lwb, par, o2, qbase);
    k_fgemm_mfma<<<mtiles*64, 256, 0, stream>>>(o2, woutT, part, qbase, qlim, mtiles);
  }
  k_ln<<<NQ, 256, 0, stream>>>(part, qf, b_out, ln_g, ln_b, (float*)d_out);
}

// Round 4
// 396.045 us; speedup vs baseline: 3.4782x; 1.2882x over previous
//
#include <hip/hip_runtime.h>
#include <hip/hip_bf16.h>
#include <cstdint>
#include <cstddef>

#define DI __device__ __forceinline__

// ---------- constants ----------
#define NN 500
#define NQ 2000           // B*N
#define GTOT 32768        // G*TOTAL
#define LN_EPS 1e-5f

typedef __attribute__((ext_vector_type(8))) short short8v;
typedef __attribute__((ext_vector_type(4))) float f32x4;

DI unsigned short f2bf(float f){
  unsigned u = __float_as_uint(f);
  return (unsigned short)((u + 0x7fffu + ((u>>16)&1u)) >> 16);
}
DI float bf2f(unsigned short s){ return __uint_as_float(((unsigned)s)<<16); }

// block-wide (256 thr = 4 waves) sum of s, s2
DI void bred256(float& s, float& s2, float* red, int tid){
  #pragma unroll
  for(int off=32; off; off>>=1){
    s  += __shfl_xor(s,  off, 64);
    s2 += __shfl_xor(s2, off, 64);
  }
  int w = tid>>6;
  if((tid&63)==0){ red[w*2]=s; red[w*2+1]=s2; }
  __syncthreads();
  s  = red[0]+red[2]+red[4]+red[6];
  s2 = red[1]+red[3]+red[5]+red[7];
  __syncthreads();
}

// ---------- K0: feature transpose (B,C,H,W) f32 -> (B*G,H,W,64) bf16 ----------
__global__ __launch_bounds__(256) void k_transpose(const float* __restrict__ src,
    unsigned short* __restrict__ dst, int H, int W){
  __shared__ float tile[64][161];
  int bg = blockIdx.x / H, h = blockIdx.x % H;
  int b = bg >> 2, g = bg & 3;
  const float* s = src + (((size_t)(b*256 + g*64))*H + h)*(size_t)W;
  for(int idx=threadIdx.x; idx<64*W; idx+=256){
    int c = idx / W, w = idx - c*W;
    tile[c][w] = s[(size_t)c*H*W + w];
  }
  __syncthreads();
  unsigned short* d = dst + ((size_t)bg*H + h)*(size_t)W*64;
  for(int idx=threadIdx.x; idx<64*W; idx+=256){
    int w = idx>>6, c = idx&63;
    d[idx] = f2bf(tile[c][w]);
  }
}

// ---------- K1: offset GEMM + sample coords + level softmax ----------
__global__ __launch_bounds__(384) void k_off(const float* __restrict__ qf,
    const float* __restrict__ xyzr, const float* __restrict__ w_off,
    const float* __restrict__ b_off, float2* __restrict__ xyb, float4* __restrict__ lwb){
  __shared__ float qs[8][256];
  __shared__ float os[8][384];
  int q0 = blockIdx.x*8, tid = threadIdx.x;
  for(int idx=tid; idx<2048; idx+=384){
    int qq = idx>>8, k = idx&255;
    qs[qq][k] = qf[(size_t)(q0+qq)*256 + k];
  }
  __syncthreads();
  {
    int j = tid;
    float acc[8];
    #pragma unroll
    for(int i=0;i<8;i++) acc[i]=0.f;
    for(int k=0;k<256;k++){
      float w = w_off[(size_t)k*384 + j];
      #pragma unroll
      for(int qq=0;qq<8;qq++) acc[qq] += qs[qq][k]*w;
    }
    float bb = b_off[j];
    #pragma unroll
    for(int qq=0;qq<8;qq++) os[qq][j] = acc[qq] + bb;
  }
  __syncthreads();
  for(int idx=tid; idx<1024; idx+=384){
    int qq = idx>>7, gp = idx&127;
    int q = q0+qq;
    float4 xr = *(const float4*)&xyzr[(size_t)q*4];
    float rw = exp2f(xr.z - 0.5f*xr.w);
    float rh = exp2f(xr.z + 0.5f*xr.w);
    float sx = xr.x + os[qq][gp*3+0]*rw;
    float sy = xr.y + os[qq][gp*3+1]*rh;
    float lvl = xr.z + os[qq][gp*3+2] - 3.0f;
    float d0=lvl, d1=lvl-1.f, d2=lvl-2.f, d3=lvl-3.f;
    float e0=-0.5f*d0*d0, e1=-0.5f*d1*d1, e2=-0.5f*d2*d2, e3=-0.5f*d3*d3;
    float m = fmaxf(fmaxf(e0,e1),fmaxf(e2,e3));
    float x0=expf(e0-m), x1=expf(e1-m), x2=expf(e2-m), x3=expf(e3-m);
    float inv = 1.f/(x0+x1+x2+x3);
    xyb[(size_t)q*128+gp] = make_float2(sx,sy);
    lwb[(size_t)q*128+gp] = make_float4(x0*inv, x1*inv, x2*inv, x3*inv);
  }
}

// ---------- K-cvt: qf f32[2000][256] -> bf16[2048][256], pad rows zeroed ----------
__global__ __launch_bounds__(256) void k_cvtqf(const float* __restrict__ qf,
    unsigned short* __restrict__ qfb){
  int idx = blockIdx.x*256 + threadIdx.x;   // one per 8 elems; 65536 total
  size_t base = (size_t)idx*8;
  int row = idx >> 5;
  ushort4 lo, hi;
  if(row < NQ){
    float4 a = *(const float4*)(qf + base);
    float4 b = *(const float4*)(qf + base + 4);
    lo.x=f2bf(a.x); lo.y=f2bf(a.y); lo.z=f2bf(a.z); lo.w=f2bf(a.w);
    hi.x=f2bf(b.x); hi.y=f2bf(b.y); hi.z=f2bf(b.z); hi.w=f2bf(b.w);
  } else {
    lo.x=lo.y=lo.z=lo.w=0; hi.x=hi.y=hi.z=hi.w=0;
  }
  *(ushort4*)(qfb + base) = lo;
  *(ushort4*)(qfb + base + 4) = hi;
}

// ---------- K-trcvt: src f32 [R][C] -> dst bf16 [C][R] (R,C multiples of 64) ----------
__global__ __launch_bounds__(256) void k_trcvt(const float* __restrict__ src,
    unsigned short* __restrict__ dst, int R, int C){
  __shared__ float tile[64][65];
  int ctiles = C >> 6;
  int rt = blockIdx.x / ctiles, ct = blockIdx.x % ctiles;
  int r0 = rt<<6, c0 = ct<<6;
  int tid = threadIdx.x;
  int lr = tid>>6, lc = tid&63;
  #pragma unroll
  for(int i=0;i<16;i++)
    tile[lr + i*4][lc] = src[(size_t)(r0+lr+i*4)*C + c0+lc];
  __syncthreads();
  #pragma unroll
  for(int i=0;i<16;i++)
    dst[(size_t)(c0+lr+i*4)*R + r0+lc] = f2bf(tile[lc][lr+i*4]);
}

// ---------- shared MFMA tile compute: 64x64 tile, BK=128, swizzled LDS ----------
DI f32x4 mfma16(short8v a, short8v b, f32x4 c){
  return __builtin_amdgcn_mfma_f32_16x16x32_bf16(a, b, c, 0, 0, 0);
}

DI void mma_step(const short* lsA, const short* lsB, int wm, int wn, int lane,
                 f32x4 acc[2][2]){
  #pragma unroll
  for(int ks=0; ks<4; ks++){
    short8v a[2], b[2];
    #pragma unroll
    for(int i=0;i<2;i++){
      int ra = wm*32 + i*16 + (lane&15);
      int ba = (ra<<8) + ks*64 + ((lane>>4)<<4);
      ba ^= (ra&7)<<4;
      a[i] = *(const short8v*)((const char*)lsA + ba);
      int rb = wn*32 + i*16 + (lane&15);
      int bb = (rb<<8) + ks*64 + ((lane>>4)<<4);
      bb ^= (rb&7)<<4;
      b[i] = *(const short8v*)((const char*)lsB + bb);
    }
    #pragma unroll
    for(int mi=0;mi<2;mi++)
      #pragma unroll
      for(int ni=0;ni<2;ni++)
        acc[mi][ni] = mfma16(a[mi], b[ni], acc[mi][ni]);
  }
}

// stage a 64x128 bf16 tile (global row-major, row stride ldk shorts) into swizzled LDS
DI void stage64x128(const unsigned short* __restrict__ g, size_t row0, size_t ldk,
                    int k0, short* lds, int tid){
  #pragma unroll
  for(int i=0;i<4;i++){
    int idx = tid + i*256;
    int r = idx>>4, c = idx&15;
    uint4 v = *(const uint4*)(g + (row0 + r)*ldk + k0 + c*8);
    int byte = (r<<8) + (c<<4);
    byte ^= (r&7)<<4;
    *(uint4*)((char*)lds + byte) = v;
  }
}

// XCD-affinity remap: consecutive logical blocks (which share B-tiles) land on one XCD.
DI int xcd_remap(int bid, int nwg){
  return ((bid & 7) * (nwg >> 3)) + (bid >> 3);   // requires nwg % 8 == 0
}

// ---------- K2: params GEMM via MFMA: par[q][32768] = qfb @ wpgT^T + b_pg ----------
__global__ __launch_bounds__(256) void k_pgemm_mfma(const unsigned short* __restrict__ qfb,
    const unsigned short* __restrict__ wpgT, const float* __restrict__ b_pg,
    unsigned short* __restrict__ par, int qbase, int qlim, int mtiles){
  __shared__ short lsA[64*128], lsB[64*128];
  int bid = xcd_remap(blockIdx.x, gridDim.x);
  int mt = bid % mtiles, nt = bid / mtiles;
  int m0 = mt*64;
  size_t n0 = (size_t)nt*64;
  int tid = threadIdx.x, lane = tid&63, wv = tid>>6;
  int wm = wv>>1, wn = wv&1;
  f32x4 acc[2][2] = {};
  #pragma unroll
  for(int kb=0; kb<2; kb++){
    int k0 = kb*128;
    stage64x128(qfb, (size_t)(qbase+m0), 256, k0, lsA, tid);
    stage64x128(wpgT, n0, 256, k0, lsB, tid);
    __syncthreads();
    mma_step(lsA, lsB, wm, wn, lane, acc);
    __syncthreads();
  }
  int colb = (int)n0 + wn*32 + (lane&15);
  int rowb = m0 + wm*32 + ((lane>>4)<<2);
  #pragma unroll
  for(int ni=0;ni<2;ni++){
    int col = colb + ni*16;
    float bias = b_pg[col];
    #pragma unroll
    for(int mi=0;mi<2;mi++){
      #pragma unroll
      for(int j=0;j<4;j++){
        int r = rowb + mi*16 + j;
        if(qbase + r < qlim)
          par[(size_t)r*GTOT + col] = f2bf(acc[mi][ni][j] + bias);
      }
    }
  }
}

// ---------- K4: final GEMM via MFMA, K-split x16 -> f32 partials ----------
__global__ __launch_bounds__(256) void k_fgemm_mfma(const unsigned short* __restrict__ A,
    const unsigned short* __restrict__ woutT, float* __restrict__ part,
    int qbase, int qlim, int mtiles){
  __shared__ short lsA[64*128], lsB[64*128];
  int bid = xcd_remap(blockIdx.x, gridDim.x);
  int mt = bid % mtiles; bid /= mtiles;
  int nt = bid & 3, ks = bid >> 2;
  int m0 = mt*64, n0 = nt*64;
  int tid = threadIdx.x, lane = tid&63, wv = tid>>6;
  int wm = wv>>1, wn = wv&1;
  f32x4 acc[2][2] = {};
  int kbase = ks*2048;
  for(int k0=kbase; k0<kbase+2048; k0+=128){
    stage64x128(A, (size_t)m0, GTOT, k0, lsA, tid);
    stage64x128(woutT, (size_t)n0, GTOT, k0, lsB, tid);
    __syncthreads();
    mma_step(lsA, lsB, wm, wn, lane, acc);
    __syncthreads();
  }
  float* pp = part + (size_t)ks*NQ*256;
  int colb = n0 + wn*32 + (lane&15);
  int rowb = m0 + wm*32 + ((lane>>4)<<2);
  #pragma unroll
  for(int mi=0;mi<2;mi++)
    #pragma unroll
    for(int ni=0;ni<2;ni++)
      #pragma unroll
      for(int j=0;j<4;j++){
        int r = rowb + mi*16 + j;
        if(qbase + r < qlim)
          pp[(size_t)(qbase + r)*256 + colb + ni*16] = acc[mi][ni][j];
      }
}

// ---------- K3: sampling + M/S mixing via MFMA + two group-LN+relu -> out2 bf16 ----------
// block = one (q,g), 4 waves. LDS pool reused across phases.
__global__ __launch_bounds__(256) void k_mix(const unsigned short* __restrict__ featT,
    const float2* __restrict__ xyb, const float4* __restrict__ lwb,
    const unsigned short* __restrict__ par, unsigned short* __restrict__ out2,
    int qbase){
  // pool: offW[128][8] f32 (4KB) | xs[32][72] bf16 (4.6KB) | Ms[64][72] bf16 (9.2KB) | o1t[64][40] bf16 (5.1KB)
  // o2s[128][72] bf16 (18.4KB) aliases the pool after the phase-C barrier.
  __shared__ __align__(16) char poolA[23040];
  __shared__ __align__(16) unsigned short Ss[128*40];   // S natural [o][p], pad 40
  __shared__ float red[8];
  float* offW = (float*)poolA;
  unsigned short* xs  = (unsigned short*)(poolA + 4096);
  unsigned short* Ms  = (unsigned short*)(poolA + 4096 + 4608);
  unsigned short* o1t = (unsigned short*)(poolA + 4096 + 4608 + 9216);
  unsigned short* o2s = (unsigned short*)poolA;

  int lq = blockIdx.x >> 2, g = blockIdx.x & 3;
  int q = qbase + lq;
  int b = q / NN;
  int bg = b*4 + g;
  int tid = threadIdx.x;
  int lane = tid & 63, wv = tid >> 6;

  const int HH[4] = {100,50,25,13};
  const int WW[4] = {160,80,40,20};
  const float IS[4] = {0.125f, 0.0625f, 0.03125f, 0.015625f};
  const int LO[4] = {0, 16384000, 20480000, 21504000};

  // issue M/S loads (coalesced 16B per thread, 2 rounds each)
  const unsigned short* pb = par + (size_t)lq*GTOT + (size_t)g*8192;
  uint4 mraw0 = *(const uint4*)(pb + tid*8);
  uint4 mraw1 = *(const uint4*)(pb + 2048 + tid*8);
  uint4 sraw0 = *(const uint4*)(pb + 4096 + tid*8);
  uint4 sraw1 = *(const uint4*)(pb + 6144 + tid*8);

  // precompute gather offsets/weights: thread t<128 handles (p=t>>2, l=t&3)
  if(tid < 128){
    int p = tid >> 2, l = tid & 3;
    int pi = q*128 + g*32 + p;
    float2 xy = xyb[pi];
    float lw4 = ((const float*)lwb)[(size_t)pi*4 + l];
    int H = HH[l], W = WW[l];
    float px = xy.x*IS[l] - 0.5f;
    float py = xy.y*IS[l] - 0.5f;
    float xf = floorf(px), yf = floorf(py);
    float wx = px - xf, wy = py - yf;
    int x0 = (int)xf, y0 = (int)yf;
    int x1 = x0 + 1, y1 = y0 + 1;
    bool vx0 = (x0>=0)&&(x0<W), vx1 = (x1>=0)&&(x1<W);
    bool vy0 = (y0>=0)&&(y0<H), vy1 = (y1>=0)&&(y1<H);
    int x0c = min(max(x0,0),W-1), x1c = min(max(x1,0),W-1);
    int y0c = min(max(y0,0),H-1), y1c = min(max(y1,0),H-1);
    int base = LO[l] + bg*H*W*64;
    float* e = offW + tid*8;
    e[0] = __int_as_float(base + (y0c*W + x0c)*64);
    e[1] = __int_as_float(base + (y0c*W + x1c)*64);
    e[2] = __int_as_float(base + (y1c*W + x0c)*64);
    e[3] = __int_as_float(base + (y1c*W + x1c)*64);
    e[4] = (1.f-wx)*(1.f-wy)*lw4*(float)(vx0&&vy0);
    e[5] = wx*(1.f-wy)*lw4*(float)(vx1&&vy0);
    e[6] = (1.f-wx)*wy*lw4*(float)(vx0&&vy1);
    e[7] = wx*wy*lw4*(float)(vx1&&vy1);
  }

  // deposit M into Ms[64][72] (row c, col d), S into Ss[128][40] (row o, col p)
  {
    int idx0 = tid*8;
    int c0 = idx0>>6, d0 = idx0&63;
    *(uint4*)(Ms + c0*72 + d0) = mraw0;
    int idx1 = 2048 + tid*8;
    int c1 = idx1>>6, d1 = idx1&63;
    *(uint4*)(Ms + c1*72 + d1) = mraw1;
    int o0 = idx0>>5, p0 = idx0&31;
    *(uint4*)(Ss + o0*40 + p0) = sraw0;
    int o1_ = idx1>>5, p1 = idx1&31;
    *(uint4*)(Ss + o1_*40 + p1) = sraw1;
  }
  __syncthreads();

  // Phase A: gather. wave wv handles p = wv*8 .. wv*8+7; lane = channel.
  #pragma unroll
  for(int i=0;i<8;i++){
    int p = wv*8 + i;
    const float* e = offW + p*32;   // 4 levels x 8
    float acc = 0.f;
    #pragma unroll
    for(int l=0;l<4;l++){
      const float* el = e + l*8;
      int o00 = __float_as_int(el[0]), o01 = __float_as_int(el[1]);
      int o10 = __float_as_int(el[2]), o11 = __float_as_int(el[3]);
      acc += el[4]*bf2f(featT[o00 + lane]);
      acc += el[5]*bf2f(featT[o01 + lane]);
      acc += el[6]*bf2f(featT[o10 + lane]);
      acc += el[7]*bf2f(featT[o11 + lane]);
    }
    xs[p*72 + lane] = f2bf(acc);
  }
  __syncthreads();

  int r = lane & 15, q4 = lane >> 4;

  // Phase B: out1 = x(32x64) @ M(64x64); wave wv owns column strip d = wv*16..+15
  {
    short8v af00 = *(const short8v*)(xs + r*72 + q4*8);            // mi0 ks0
    short8v af01 = *(const short8v*)(xs + r*72 + 32 + q4*8);       // mi0 ks1
    short8v af10 = *(const short8v*)(xs + (16+r)*72 + q4*8);       // mi1 ks0
    short8v af11 = *(const short8v*)(xs + (16+r)*72 + 32 + q4*8);  // mi1 ks1
    short8v bm0, bm1;
    #pragma unroll
    for(int j=0;j<8;j++){
      bm0[j] = (short)Ms[(8*q4+j)*72 + wv*16 + r];
      bm1[j] = (short)Ms[(32+8*q4+j)*72 + wv*16 + r];
    }
    f32x4 a0 = {}, a1 = {};
    a0 = mfma16(af00, bm0, a0); a0 = mfma16(af01, bm1, a0);
    a1 = mfma16(af10, bm0, a1); a1 = mfma16(af11, bm1, a1);

    float s = 0.f, s2 = 0.f;
    #pragma unroll
    for(int v=0;v<4;v++){ s += a0[v]+a1[v]; s2 += a0[v]*a0[v] + a1[v]*a1[v]; }
    bred256(s, s2, red, tid);
    float mean = s*(1.f/2048.f);
    float var = s2*(1.f/2048.f) - mean*mean;
    float rs = rsqrtf(var + LN_EPS);
    #pragma unroll
    for(int v=0;v<4;v++){
      float f0 = (a0[v]-mean)*rs; f0 = f0>0.f ? f0 : 0.f;
      float f1 = (a1[v]-mean)*rs; f1 = f1>0.f ? f1 : 0.f;
      o1t[(wv*16+r)*40 + 4*q4 + v] = f2bf(f0);        // p = 4*q4+v (mi=0)
      o1t[(wv*16+r)*40 + 16 + 4*q4 + v] = f2bf(f1);   // p = 16+4*q4+v (mi=1)
    }
  }
  __syncthreads();

  // Phase C: out2 = S(128x32) @ out1(32x64); wave wv owns rows o = wv*32..+31
  {
    short8v sa0 = *(const short8v*)(Ss + ((wv*2+0)*16 + r)*40 + q4*8);
    short8v sa1 = *(const short8v*)(Ss + ((wv*2+1)*16 + r)*40 + q4*8);
    short8v ov0 = *(const short8v*)(o1t + (r)*40 + q4*8);
    short8v ov1 = *(const short8v*)(o1t + (16+r)*40 + q4*8);
    short8v ov2 = *(const short8v*)(o1t + (32+r)*40 + q4*8);
    short8v ov3 = *(const short8v*)(o1t + (48+r)*40 + q4*8);
    f32x4 c2[2][4] = {};
    c2[0][0] = mfma16(sa0, ov0, c2[0][0]); c2[0][1] = mfma16(sa0, ov1, c2[0][1]);
    c2[0][2] = mfma16(sa0, ov2, c2[0][2]); c2[0][3] = mfma16(sa0, ov3, c2[0][3]);
    c2[1][0] = mfma16(sa1, ov0, c2[1][0]); c2[1][1] = mfma16(sa1, ov1, c2[1][1]);
    c2[1][2] = mfma16(sa1, ov2, c2[1][2]); c2[1][3] = mfma16(sa1, ov3, c2[1][3]);

    float s = 0.f, s2 = 0.f;
    #pragma unroll
    for(int m=0;m<2;m++)
      #pragma unroll
      for(int ni=0;ni<4;ni++)
        #pragma unroll
        for(int v=0;v<4;v++){ float x = c2[m][ni][v]; s += x; s2 += x*x; }
    bred256(s, s2, red, tid);   // barrier inside: all o1t/xs/Ms reads complete before o2s writes
    float mean = s*(1.f/8192.f);
    float var = s2*(1.f/8192.f) - mean*mean;
    float rs = rsqrtf(var + LN_EPS);
    #pragma unroll
    for(int m=0;m<2;m++)
      #pragma unroll
      for(int ni=0;ni<4;ni++)
        #pragma unroll
        for(int v=0;v<4;v++){
          float x = (c2[m][ni][v]-mean)*rs; x = x>0.f ? x : 0.f;
          int o = (wv*2+m)*16 + 4*q4 + v;
          int d = ni*16 + r;
          o2s[o*72 + d] = f2bf(x);
        }
  }
  __syncthreads();

  // coalesced store: 128 rows x 64 cols
  unsigned short* og = out2 + (size_t)lq*GTOT + (size_t)g*8192;
  #pragma unroll
  for(int i=0;i<32;i++){
    int row = wv*32 + i;
    og[row*64 + lane] = o2s[row*72 + lane];
  }
}

// ---------- K5: K-split reduce + bias + residual + LayerNorm ----------
__global__ __launch_bounds__(256) void k_ln(const float* __restrict__ part,
    const float* __restrict__ qf, const float* __restrict__ b_out,
    const float* __restrict__ ln_g, const float* __restrict__ ln_b,
    float* __restrict__ out){
  __shared__ float red[8];
  int q = blockIdx.x, j = threadIdx.x;
  float s = qf[(size_t)q*256 + j] + b_out[j];
  #pragma unroll
  for(int ks=0; ks<16; ks++) s += part[((size_t)ks*NQ + q)*256 + j];
  float a = s, a2 = s*s;
  bred256(a, a2, red, j);
  float mean = a*(1.f/256.f);
  float var = a2*(1.f/256.f) - mean*mean;
  float rs = rsqrtf(var + LN_EPS);
  out[(size_t)q*256 + j] = (s-mean)*rs*ln_g[j] + ln_b[j];
}

// ---------- launch ----------
extern "C" void kernel_launch(void* const* d_in, const int* in_sizes, int n_in,
                              void* d_out, int out_size, void* d_ws, size_t ws_size,
                              hipStream_t stream) {
  const float* feat0 = (const float*)d_in[0];
  const float* feat1 = (const float*)d_in[1];
  const float* feat2 = (const float*)d_in[2];
  const float* feat3 = (const float*)d_in[3];
  const float* qf    = (const float*)d_in[4];
  const float* xyzr  = (const float*)d_in[5];
  const float* w_off = (const float*)d_in[6];
  const float* b_off = (const float*)d_in[7];
  const float* w_pg  = (const float*)d_in[8];
  const float* b_pg  = (const float*)d_in[9];
  const float* w_out = (const float*)d_in[10];
  const float* b_out = (const float*)d_in[11];
  const float* ln_g  = (const float*)d_in[12];
  const float* ln_b  = (const float*)d_in[13];

  size_t off = 0;
  auto alloc = [&](size_t bytes){ size_t r = off; off = (off + bytes + 255) & ~255ull; return r; };
  size_t oFEAT = alloc(43540480ull);              // featT bf16
  size_t oXY   = alloc((size_t)NQ*128*8);         // float2
  size_t oLW   = alloc((size_t)NQ*128*16);        // float4
  size_t oPART = alloc((size_t)16*NQ*256*4);      // f32 partials
  size_t oQFB  = alloc((size_t)2048*256*2);       // qf bf16 padded
  size_t oWPGT = alloc((size_t)GTOT*256*2);       // w_pg^T bf16
  size_t oWOUT = alloc((size_t)256*GTOT*2);       // w_out^T bf16
  size_t fixedEnd = off;

  int NC = 0; size_t cb = 0; int qcount = 0, qpad = 0;
  for (int t = 1; t <= 8; t *= 2) {
    int qc = NQ / t;
    int qp = (qc + 63) & ~63;
    size_t c = (((size_t)qp*GTOT*2) + 255) & ~255ull;
    if (fixedEnd + 2*c <= ws_size) { NC = t; cb = c; qcount = qc; qpad = qp; break; }
  }
  if (NC == 0) return;
  size_t oPAR = fixedEnd, oOUT2 = fixedEnd + cb;

  char* ws = (char*)d_ws;
  unsigned short* featT = (unsigned short*)(ws + oFEAT);
  float2* xyb = (float2*)(ws + oXY);
  float4* lwb = (float4*)(ws + oLW);
  float* part = (float*)(ws + oPART);
  unsigned short* qfb  = (unsigned short*)(ws + oQFB);
  unsigned short* wpgT = (unsigned short*)(ws + oWPGT);
  unsigned short* woutT= (unsigned short*)(ws + oWOUT);
  unsigned short* par  = (unsigned short*)(ws + oPAR);
  unsigned short* o2   = (unsigned short*)(ws + oOUT2);

  k_transpose<<<16*100, 256, 0, stream>>>(feat0, featT + 0ull,        100, 160);
  k_transpose<<<16*50,  256, 0, stream>>>(feat1, featT + 16384000ull,  50,  80);
  k_transpose<<<16*25,  256, 0, stream>>>(feat2, featT + 20480000ull,  25,  40);
  k_transpose<<<16*13,  256, 0, stream>>>(feat3, featT + 21504000ull,  13,  20);
  k_off<<<250, 384, 0, stream>>>(qf, xyzr, w_off, b_off, xyb, lwb);
  k_cvtqf<<<256, 256, 0, stream>>>(qf, qfb);
  k_trcvt<<<2048, 256, 0, stream>>>(w_pg,  wpgT, 256, GTOT);   // [256][32768] -> [32768][256]
  k_trcvt<<<2048, 256, 0, stream>>>(w_out, woutT, GTOT, 256);  // [32768][256] -> [256][32768]

  int mtiles = qpad / 64;
  for (int c = 0; c < NC; ++c) {
    int qbase = c * qcount;
    int qlim  = qbase + qcount;
    k_pgemm_mfma<<<mtiles*512, 256, 0, stream>>>(qfb, wpgT, b_pg, par, qbase, qlim, mtiles);
    k_mix<<<qcount*4, 256, 0, stream>>>(featT, xyb, lwb, par, o2, qbase);
    k_fgemm_mfma<<<mtiles*64, 256, 0, stream>>>(o2, woutT, part, qbase, qlim, mtiles);
  }
  k_ln<<<NQ, 256, 0, stream>>>(part, qf, b_out, ln_g, ln_b, (float*)d_out);
}